// Round 9
// baseline (130.991 us; speedup 1.0000x reference)
//
#include <hip/hip_runtime.h>

#define N_NODES 100000
#define N_EDGES 600000
#define N_PAD   100352      // N_NODES rounded to 1024 (scan tiles)
#define NB1     98          // N_PAD / 1024
#define G1_BLOCKS 3125      // N_NODES / 32 exactly
#define HIST_BLOCKS 2344    // ceil(600000/256)
#define MID_BLOCKS 3125     // N_NODES / 32 exactly

typedef __bf16 bf16x8 __attribute__((ext_vector_type(8)));
typedef float  f32x4  __attribute__((ext_vector_type(4)));
typedef unsigned short u16x8 __attribute__((ext_vector_type(8)));
typedef unsigned short u16x4 __attribute__((ext_vector_type(4)));

__device__ inline unsigned short f2bf(float f) {
    __bf16 h = (__bf16)f;
    return __builtin_bit_cast(unsigned short, h);
}
__device__ inline float bf2f(unsigned short u) {
    return __builtin_bit_cast(float, ((unsigned)u) << 16);
}
__device__ inline bf16x8 ldfrag_bf16(const unsigned short* p) {
    u16x8 v = *(const u16x8*)p;
    return __builtin_bit_cast(bf16x8, v);
}

// ---------------------------------------------------------------------------
// prep: zero deg8 (8 banks) + gbase, convert W1/W2 to bf16
// grid = 392 x 256 = 100352 = N_PAD threads
// ---------------------------------------------------------------------------
__global__ __launch_bounds__(256) void prep(
    const float* __restrict__ w1l, const float* __restrict__ w1r,
    const float* __restrict__ w2l, const float* __restrict__ w2r,
    unsigned short* __restrict__ wbf1, unsigned short* __restrict__ wbf2,
    int* __restrict__ deg8, int* __restrict__ gbase)
{
    int i = blockIdx.x * 256 + threadIdx.x;
    #pragma unroll
    for (int bk = 0; bk < 8; ++bk) deg8[bk * N_PAD + i] = 0;
    if (i == 0) gbase[0] = 0;
    if (i < 16384) {
        int row = i >> 7, k = i & 127;
        float v = (row < 64) ? w1l[(row << 7) + k] : w1r[((row - 64) << 7) + k];
        wbf1[i] = f2bf(v);
    } else if (i < 20480) {
        int j = i - 16384;
        int row = j >> 6, k = j & 63;
        float v = (row < 32) ? w2l[(row << 6) + k] : w2r[((row - 32) << 6) + k];
        wbf2[j] = f2bf(v);
    }
}

// ---------------------------------------------------------------------------
// gemm1: layer-1 MFMA GEMM via 8KB swizzled bf16 LDS tile, 32 nodes/block.
// All 8 W-frags preloaded to VGPRs -> k-loop is pure ds_read + MFMA.
// ---------------------------------------------------------------------------
__global__ __launch_bounds__(256) void gemm1(
    const float* __restrict__ x,
    const unsigned short* __restrict__ wbf1,   // [128][128] bf16
    unsigned short* __restrict__ xl,
    unsigned short* __restrict__ xr)
{
    __shared__ unsigned short xs[32 * 128];    // 8KB, XOR-swizzled rows of 256B
    const int tid   = threadIdx.x;
    const int nbase = blockIdx.x * 32;         // exact: 100000 = 3125*32
    const int wv   = tid >> 6;
    const int l    = tid & 63;
    const int lrow = l & 15;
    const int hi   = l >> 4;

    // ---- preload the wave's full W slice: 8 frags = 32 VGPR ----
    bf16x8 wfrag[2][4];
    #pragma unroll
    for (int ft = 0; ft < 2; ++ft)
        #pragma unroll
        for (int kt = 0; kt < 4; ++kt)
            wfrag[ft][kt] = ldfrag_bf16(
                wbf1 + (wv * 32 + ft * 16 + lrow) * 128 + kt * 32 + hi * 8);

    // ---- stage x-tile: 2 rounds x 16B(bf16)/thread, dense global reads ----
    #pragma unroll
    for (int j = 0; j < 2; ++j) {
        const int L   = j * 4096 + tid * 16;
        const int row = L >> 8;
        const int off = L & 255;
        const float* src = x + (size_t)(nbase + row) * 128 + (off >> 1);
        float4 u = *(const float4*)src;
        float4 w = *(const float4*)(src + 4);
        u16x8 o;
        o[0]=f2bf(u.x); o[1]=f2bf(u.y); o[2]=f2bf(u.z); o[3]=f2bf(u.w);
        o[4]=f2bf(w.x); o[5]=f2bf(w.y); o[6]=f2bf(w.z); o[7]=f2bf(w.w);
        *(u16x8*)((char*)xs + row * 256 + (off ^ ((row & 7) << 4))) = o;
    }
    __syncthreads();

    f32x4 acc[2][2];                           // [ntile][ftile]
    #pragma unroll
    for (int nt = 0; nt < 2; ++nt)
        #pragma unroll
        for (int ft = 0; ft < 2; ++ft) acc[nt][ft] = (f32x4){0.f,0.f,0.f,0.f};

    #pragma unroll
    for (int kt = 0; kt < 4; ++kt) {
        const int koff = kt * 64 + hi * 16;
        const int r0 = lrow, r1 = 16 + lrow;
        bf16x8 b0 = __builtin_bit_cast(bf16x8, *(const u16x8*)
            ((const char*)xs + r0 * 256 + (koff ^ ((r0 & 7) << 4))));
        bf16x8 b1 = __builtin_bit_cast(bf16x8, *(const u16x8*)
            ((const char*)xs + r1 * 256 + (koff ^ ((r1 & 7) << 4))));
        #pragma unroll
        for (int ft = 0; ft < 2; ++ft) {
            acc[0][ft] = __builtin_amdgcn_mfma_f32_16x16x32_bf16(wfrag[ft][kt], b0, acc[0][ft], 0, 0, 0);
            acc[1][ft] = __builtin_amdgcn_mfma_f32_16x16x32_bf16(wfrag[ft][kt], b1, acc[1][ft], 0, 0, 0);
        }
    }

    // ---- D: col = lane&15 -> node, row = hi*4 + r -> feat ----
    #pragma unroll
    for (int nt = 0; nt < 2; ++nt) {
        const int node = nbase + nt * 16 + lrow;
        #pragma unroll
        for (int ft = 0; ft < 2; ++ft) {
            const int feat = wv * 32 + ft * 16 + hi * 4;
            u16x4 p;
            p[0] = f2bf(acc[nt][ft][0]); p[1] = f2bf(acc[nt][ft][1]);
            p[2] = f2bf(acc[nt][ft][2]); p[3] = f2bf(acc[nt][ft][3]);
            if (wv < 2) *(u16x4*)&xl[node * 64 + feat]        = p;
            else        *(u16x4*)&xr[node * 64 + (feat - 64)] = p;
        }
    }
}

// ---------------------------------------------------------------------------
// hist: XCD-privatized degree histogram (bank = blockIdx & 7; blockIdx
// round-robins across the 8 XCDs -> each bank's lines stay in one L2)
// ---------------------------------------------------------------------------
__global__ __launch_bounds__(256) void hist(const int* __restrict__ ei,
                                            int* __restrict__ deg8)
{
    const int blk = blockIdx.x;
    int e = blk * 256 + threadIdx.x;
    if (e >= N_EDGES) return;
    atomicAdd(&deg8[(blk & 7) * N_PAD + ei[N_EDGES + e]], 1);
}

// ---------------------------------------------------------------------------
// scan: sum 8 banks -> deg; block scan + atomic global base -> start;
// per-bank exclusive prefix -> cursor8 (exact allocation ranges)
// ---------------------------------------------------------------------------
__global__ __launch_bounds__(256) void scan_atomic(
    const int* __restrict__ deg8, int* __restrict__ gbase,
    int* __restrict__ deg, int* __restrict__ start, int* __restrict__ cursor8)
{
    __shared__ int s[256];
    __shared__ int base_s;
    int b = blockIdx.x, tid = threadIdx.x;
    int i = b * 1024 + tid * 4;
    int4 d8[8];
    #pragma unroll
    for (int bk = 0; bk < 8; ++bk) d8[bk] = *(const int4*)&deg8[bk * N_PAD + i];
    int4 tot = d8[0];
    #pragma unroll
    for (int bk = 1; bk < 8; ++bk) {
        tot.x += d8[bk].x; tot.y += d8[bk].y; tot.z += d8[bk].z; tot.w += d8[bk].w;
    }
    int p0 = tot.x, p1 = p0 + tot.y, p2 = p1 + tot.z, p3 = p2 + tot.w;
    s[tid] = p3;
    __syncthreads();
    for (int off = 1; off < 256; off <<= 1) {
        int t = (tid >= off) ? s[tid - off] : 0;
        __syncthreads();
        s[tid] += t;
        __syncthreads();
    }
    if (tid == 255) base_s = atomicAdd(gbase, s[255]);
    int excl = s[tid] - p3;
    __syncthreads();
    int e0 = base_s + excl;
    int e1 = e0 + tot.x, e2 = e1 + tot.y, e3 = e2 + tot.z;
    *(int4*)&deg[i] = tot;
    int4 st; st.x = e0; st.y = e1; st.z = e2; st.w = e3;
    *(int4*)&start[i] = st;
    int cx = e0, cy = e1, cz = e2, cw = e3;
    #pragma unroll
    for (int bk = 0; bk < 8; ++bk) {
        int4 c; c.x = cx; c.y = cy; c.z = cz; c.w = cw;
        *(int4*)&cursor8[bk * N_PAD + i] = c;
        cx += d8[bk].x; cy += d8[bk].y; cz += d8[bk].z; cw += d8[bk].w;
    }
}

// ---------------------------------------------------------------------------
// build_csr: XCD-local cursor atomics (same bank mapping as hist)
// ---------------------------------------------------------------------------
__global__ __launch_bounds__(256) void build_csr(const int* __restrict__ ei,
                                                 int* __restrict__ cursor8,
                                                 int* __restrict__ csr_src)
{
    const int blk = blockIdx.x;
    int e = blk * 256 + threadIdx.x;
    if (e >= N_EDGES) return;
    int d = ei[N_EDGES + e];
    int pos = atomicAdd(&cursor8[(blk & 7) * N_PAD + d], 1);
    csr_src[pos] = ei[e];
}

// ---------------------------------------------------------------------------
// mid: fused gather1(+bias+right+relu) -> LDS h-tile (32 nodes) -> gemm2 MFMA
// ---------------------------------------------------------------------------
__global__ __launch_bounds__(256) void mid(
    const unsigned short* __restrict__ xl,
    const unsigned short* __restrict__ xr,
    const int* __restrict__ start,
    const int* __restrict__ deg,
    const int* __restrict__ csr_src,
    const float* __restrict__ b1l,
    const unsigned short* __restrict__ wbf2,   // [64][64] bf16
    unsigned short* __restrict__ hl,
    unsigned short* __restrict__ hr)
{
    __shared__ unsigned short hs[32 * 64];     // 4KB, swizzled rows of 128B

    const int tid = threadIdx.x;
    const int nd  = tid >> 3;                  // local node 0..31
    const int q   = tid & 7;                   // feat chunk 0..7
    const int node = blockIdx.x * 32 + nd;

    const int beg = start[node];
    const int dg  = deg[node];

    float acc[8] = {0.f,0.f,0.f,0.f,0.f,0.f,0.f,0.f};
    for (int i = 0; i < dg; ++i) {
        int s = csr_src[beg + i];
        u16x8 v = *(const u16x8*)&xl[s * 64 + 8 * q];
        #pragma unroll
        for (int j = 0; j < 8; ++j) acc[j] += bf2f(v[j]);
    }
    const float inv = 1.0f / (float)max(dg, 1);
    u16x8 rv = *(const u16x8*)&xr[node * 64 + 8 * q];
    float4 b0 = *(const float4*)&b1l[8 * q];
    float4 b1 = *(const float4*)&b1l[8 * q + 4];
    float bb[8] = {b0.x,b0.y,b0.z,b0.w,b1.x,b1.y,b1.z,b1.w};
    u16x8 hv;
    #pragma unroll
    for (int j = 0; j < 8; ++j) {
        float o = fmaf(acc[j], inv, bb[j]) + bf2f(rv[j]);
        hv[j] = f2bf(fmaxf(o, 0.f));
    }
    *(u16x8*)((char*)hs + nd * 128 + ((q * 16) ^ ((nd & 7) << 4))) = hv;
    __syncthreads();

    const int wv   = tid >> 6;
    const int l    = tid & 63;
    const int lrow = l & 15;
    const int hi   = l >> 4;

    f32x4 a0 = (f32x4){0.f,0.f,0.f,0.f};
    f32x4 a1 = (f32x4){0.f,0.f,0.f,0.f};
    #pragma unroll
    for (int kt = 0; kt < 2; ++kt) {
        const int kin = kt * 64 + hi * 16;
        bf16x8 bf0 = __builtin_bit_cast(bf16x8, *(const u16x8*)
            ((const char*)hs + lrow * 128 + (kin ^ ((lrow & 7) << 4))));
        bf16x8 bf1 = __builtin_bit_cast(bf16x8, *(const u16x8*)
            ((const char*)hs + (16 + lrow) * 128 + (kin ^ ((lrow & 7) << 4))));
        bf16x8 a = ldfrag_bf16(wbf2 + (wv * 16 + lrow) * 64 + kt * 32 + hi * 8);
        a0 = __builtin_amdgcn_mfma_f32_16x16x32_bf16(a, bf0, a0, 0, 0, 0);
        a1 = __builtin_amdgcn_mfma_f32_16x16x32_bf16(a, bf1, a1, 0, 0, 0);
    }

    const int n0 = blockIdx.x * 32 + lrow;
    const int n1 = n0 + 16;
    const int feat = wv * 16 + hi * 4;
    u16x4 p0, p1;
    p0[0]=f2bf(a0[0]); p0[1]=f2bf(a0[1]); p0[2]=f2bf(a0[2]); p0[3]=f2bf(a0[3]);
    p1[0]=f2bf(a1[0]); p1[1]=f2bf(a1[1]); p1[2]=f2bf(a1[2]); p1[3]=f2bf(a1[3]);
    if (wv < 2) {
        *(u16x4*)&hl[n0 * 32 + feat] = p0;
        *(u16x4*)&hl[n1 * 32 + feat] = p1;
    } else {
        *(u16x4*)&hr[n0 * 32 + (feat - 32)] = p0;
        *(u16x4*)&hr[n1 * 32 + (feat - 32)] = p1;
    }
}

// ---------------------------------------------------------------------------
// gather2: out[n] = (sum hl[s]) / max(deg,1) + b2 + hr[n]   (f32 out)
// ---------------------------------------------------------------------------
__global__ __launch_bounds__(256) void gather2(
    const unsigned short* __restrict__ hl,
    const int* __restrict__ start,
    const int* __restrict__ deg,
    const int* __restrict__ csr_src,
    const float* __restrict__ b2l,
    const unsigned short* __restrict__ hr,
    float* __restrict__ out)
{
    int t = blockIdx.x * 256 + threadIdx.x;
    int n = t >> 2;
    int q = t & 3;
    if (n >= N_NODES) return;
    int beg = start[n], dg = deg[n];

    float acc[8] = {0.f,0.f,0.f,0.f,0.f,0.f,0.f,0.f};
    for (int i = 0; i < dg; ++i) {
        int s = csr_src[beg + i];
        u16x8 v = *(const u16x8*)&hl[s * 32 + 8 * q];
        #pragma unroll
        for (int j = 0; j < 8; ++j) acc[j] += bf2f(v[j]);
    }
    float inv = 1.0f / (float)max(dg, 1);
    u16x8 rv = *(const u16x8*)&hr[n * 32 + 8 * q];
    float4 b0 = *(const float4*)&b2l[8 * q];
    float4 b1 = *(const float4*)&b2l[8 * q + 4];
    float bb[8] = {b0.x,b0.y,b0.z,b0.w,b1.x,b1.y,b1.z,b1.w};
    float o[8];
    #pragma unroll
    for (int j = 0; j < 8; ++j)
        o[j] = fmaf(acc[j], inv, bb[j]) + bf2f(rv[j]);
    float* op = out + n * 32 + 8 * q;
    *(float4*)op       = make_float4(o[0], o[1], o[2], o[3]);
    *(float4*)(op + 4) = make_float4(o[4], o[5], o[6], o[7]);
}

extern "C" void kernel_launch(void* const* d_in, const int* in_sizes, int n_in,
                              void* d_out, int out_size, void* d_ws, size_t ws_size,
                              hipStream_t stream)
{
    const float* x   = (const float*)d_in[0];
    const int*   ei  = (const int*)d_in[1];   // int32 (JAX x64 disabled)
    const float* w1l = (const float*)d_in[2];
    const float* b1l = (const float*)d_in[3];
    const float* w1r = (const float*)d_in[4];
    const float* w2l = (const float*)d_in[5];
    const float* b2l = (const float*)d_in[6];
    const float* w2r = (const float*)d_in[7];
    float* out = (float*)d_out;

    char* ws = (char*)d_ws;
    unsigned short* xl      = (unsigned short*)(ws + 0);          // 100000x64 bf16
    unsigned short* xr      = (unsigned short*)(ws + 12800000);
    unsigned short* hl      = (unsigned short*)(ws + 25600000);   // 100000x32 bf16
    unsigned short* hr      = (unsigned short*)(ws + 32000000);
    int*   csr_src = (int*)(ws + 38400000);                       // 2.4MB
    int*   deg8    = (int*)(ws + 40800000);                       // 8 x N_PAD
    int*   cursor8 = (int*)(ws + 44011264);                       // 8 x N_PAD
    int*   deg     = (int*)(ws + 47222528);                       // N_PAD
    int*   start   = (int*)(ws + 47623936);                       // N_PAD
    unsigned short* wbf1 = (unsigned short*)(ws + 48025344);      // [128][128]
    unsigned short* wbf2 = (unsigned short*)(ws + 48058112);      // [64][64]
    int*   gbase   = (int*)(ws + 48066304);

    // 1. prep: zero deg8/gbase + convert weights
    prep<<<392, 256, 0, stream>>>(w1l, w1r, w2l, w2r, wbf1, wbf2, deg8, gbase);
    // 2. layer-1 GEMM (W preloaded in VGPRs, LDS-staged x)
    gemm1<<<G1_BLOCKS, 256, 0, stream>>>(x, wbf1, xl, xr);
    // 3. XCD-privatized degree histogram
    hist<<<HIST_BLOCKS, 256, 0, stream>>>(ei, deg8);
    // 4. scan: deg/start/cursor8
    scan_atomic<<<NB1, 256, 0, stream>>>(deg8, gbase, deg, start, cursor8);
    // 5. bucket edges (XCD-local cursors)
    build_csr<<<HIST_BLOCKS, 256, 0, stream>>>(ei, cursor8, csr_src);
    // 6. fused gather1 + epilogue + gemm2 (h stays in LDS)
    mid<<<MID_BLOCKS, 256, 0, stream>>>(xl, xr, start, deg, csr_src, b1l, wbf2, hl, hr);
    // 7. gather2 + epilogue -> out
    gather2<<<(N_NODES * 4 + 255) / 256, 256, 0, stream>>>(hl, start, deg, csr_src, b2l, hr, out);
}

// Round 10
// 117.187 us; speedup vs baseline: 1.1178x; 1.1178x over previous
//
#include <hip/hip_runtime.h>

#define N_NODES 100000
#define N_EDGES 600000
#define N_PAD   100352      // N_NODES rounded to 1024 (scan tiles)
#define NB1     98          // N_PAD / 1024
#define G1_BLOCKS 3125      // N_NODES / 32 exactly
#define HIST_BLOCKS 2344    // ceil(600000/256)
#define MID_BLOCKS 3125     // N_NODES / 32 exactly

typedef __bf16 bf16x8 __attribute__((ext_vector_type(8)));
typedef float  f32x4  __attribute__((ext_vector_type(4)));
typedef unsigned short u16x8 __attribute__((ext_vector_type(8)));
typedef unsigned short u16x4 __attribute__((ext_vector_type(4)));

__device__ inline unsigned short f2bf(float f) {
    __bf16 h = (__bf16)f;
    return __builtin_bit_cast(unsigned short, h);
}
__device__ inline float bf2f(unsigned short u) {
    return __builtin_bit_cast(float, ((unsigned)u) << 16);
}
__device__ inline bf16x8 ldfrag_bf16(const unsigned short* p) {
    u16x8 v = *(const u16x8*)p;
    return __builtin_bit_cast(bf16x8, v);
}

// ---------------------------------------------------------------------------
// prep: zero deg8 (8 banks) + gbase, convert W1/W2 to bf16
// ---------------------------------------------------------------------------
__global__ __launch_bounds__(256) void prep(
    const float* __restrict__ w1l, const float* __restrict__ w1r,
    const float* __restrict__ w2l, const float* __restrict__ w2r,
    unsigned short* __restrict__ wbf1, unsigned short* __restrict__ wbf2,
    int* __restrict__ deg8, int* __restrict__ gbase)
{
    int i = blockIdx.x * 256 + threadIdx.x;
    #pragma unroll
    for (int bk = 0; bk < 8; ++bk) deg8[bk * N_PAD + i] = 0;
    if (i == 0) gbase[0] = 0;
    if (i < 16384) {
        int row = i >> 7, k = i & 127;
        float v = (row < 64) ? w1l[(row << 7) + k] : w1r[((row - 64) << 7) + k];
        wbf1[i] = f2bf(v);
    } else if (i < 20480) {
        int j = i - 16384;
        int row = j >> 6, k = j & 63;
        float v = (row < 32) ? w2l[(row << 6) + k] : w2r[((row - 32) << 6) + k];
        wbf2[j] = f2bf(v);
    }
}

// ---------------------------------------------------------------------------
// front: blocks [0,G1_BLOCKS) = layer-1 GEMM (LDS tile + W in VGPRs);
//        blocks [G1_BLOCKS,+HIST_BLOCKS) = XCD-privatized degree histogram.
// ---------------------------------------------------------------------------
__global__ __launch_bounds__(256) void front(
    const float* __restrict__ x,
    const unsigned short* __restrict__ wbf1,   // [128][128] bf16
    const int* __restrict__ ei,
    unsigned short* __restrict__ xl,
    unsigned short* __restrict__ xr,
    int* __restrict__ deg8)
{
    const int b   = blockIdx.x;
    const int tid = threadIdx.x;

    if (b >= G1_BLOCKS) {
        const int hb = b - G1_BLOCKS;
        int e = hb * 256 + tid;
        if (e < N_EDGES) atomicAdd(&deg8[(hb & 7) * N_PAD + ei[N_EDGES + e]], 1);
        return;
    }

    __shared__ unsigned short xs[32 * 128];    // 8KB, XOR-swizzled rows of 256B
    const int nbase = b * 32;                  // exact: 100000 = 3125*32
    const int wv   = tid >> 6;
    const int l    = tid & 63;
    const int lrow = l & 15;
    const int hi   = l >> 4;

    // preload the wave's full W slice: 8 frags = 32 VGPR
    bf16x8 wfrag[2][4];
    #pragma unroll
    for (int ft = 0; ft < 2; ++ft)
        #pragma unroll
        for (int kt = 0; kt < 4; ++kt)
            wfrag[ft][kt] = ldfrag_bf16(
                wbf1 + (wv * 32 + ft * 16 + lrow) * 128 + kt * 32 + hi * 8);

    // stage x-tile: 2 rounds x 16B(bf16)/thread, dense global reads
    #pragma unroll
    for (int j = 0; j < 2; ++j) {
        const int L   = j * 4096 + tid * 16;
        const int row = L >> 8;
        const int off = L & 255;
        const float* src = x + (size_t)(nbase + row) * 128 + (off >> 1);
        float4 u = *(const float4*)src;
        float4 w = *(const float4*)(src + 4);
        u16x8 o;
        o[0]=f2bf(u.x); o[1]=f2bf(u.y); o[2]=f2bf(u.z); o[3]=f2bf(u.w);
        o[4]=f2bf(w.x); o[5]=f2bf(w.y); o[6]=f2bf(w.z); o[7]=f2bf(w.w);
        *(u16x8*)((char*)xs + row * 256 + (off ^ ((row & 7) << 4))) = o;
    }
    __syncthreads();

    f32x4 acc[2][2];                           // [ntile][ftile]
    #pragma unroll
    for (int nt = 0; nt < 2; ++nt)
        #pragma unroll
        for (int ft = 0; ft < 2; ++ft) acc[nt][ft] = (f32x4){0.f,0.f,0.f,0.f};

    #pragma unroll
    for (int kt = 0; kt < 4; ++kt) {
        const int koff = kt * 64 + hi * 16;
        const int r0 = lrow, r1 = 16 + lrow;
        bf16x8 b0 = __builtin_bit_cast(bf16x8, *(const u16x8*)
            ((const char*)xs + r0 * 256 + (koff ^ ((r0 & 7) << 4))));
        bf16x8 b1 = __builtin_bit_cast(bf16x8, *(const u16x8*)
            ((const char*)xs + r1 * 256 + (koff ^ ((r1 & 7) << 4))));
        #pragma unroll
        for (int ft = 0; ft < 2; ++ft) {
            acc[0][ft] = __builtin_amdgcn_mfma_f32_16x16x32_bf16(wfrag[ft][kt], b0, acc[0][ft], 0, 0, 0);
            acc[1][ft] = __builtin_amdgcn_mfma_f32_16x16x32_bf16(wfrag[ft][kt], b1, acc[1][ft], 0, 0, 0);
        }
    }

    #pragma unroll
    for (int nt = 0; nt < 2; ++nt) {
        const int node = nbase + nt * 16 + lrow;
        #pragma unroll
        for (int ft = 0; ft < 2; ++ft) {
            const int feat = wv * 32 + ft * 16 + hi * 4;
            u16x4 p;
            p[0] = f2bf(acc[nt][ft][0]); p[1] = f2bf(acc[nt][ft][1]);
            p[2] = f2bf(acc[nt][ft][2]); p[3] = f2bf(acc[nt][ft][3]);
            if (wv < 2) *(u16x4*)&xl[node * 64 + feat]        = p;
            else        *(u16x4*)&xr[node * 64 + (feat - 64)] = p;
        }
    }
}

// ---------------------------------------------------------------------------
// scan: sum 8 banks -> deg; block scan + atomic global base -> start;
// per-bank exclusive prefix -> cursor8
// ---------------------------------------------------------------------------
__global__ __launch_bounds__(256) void scan_atomic(
    const int* __restrict__ deg8, int* __restrict__ gbase,
    int* __restrict__ deg, int* __restrict__ start, int* __restrict__ cursor8)
{
    __shared__ int s[256];
    __shared__ int base_s;
    int b = blockIdx.x, tid = threadIdx.x;
    int i = b * 1024 + tid * 4;
    int4 d8[8];
    #pragma unroll
    for (int bk = 0; bk < 8; ++bk) d8[bk] = *(const int4*)&deg8[bk * N_PAD + i];
    int4 tot = d8[0];
    #pragma unroll
    for (int bk = 1; bk < 8; ++bk) {
        tot.x += d8[bk].x; tot.y += d8[bk].y; tot.z += d8[bk].z; tot.w += d8[bk].w;
    }
    int p0 = tot.x, p1 = p0 + tot.y, p2 = p1 + tot.z, p3 = p2 + tot.w;
    s[tid] = p3;
    __syncthreads();
    for (int off = 1; off < 256; off <<= 1) {
        int t = (tid >= off) ? s[tid - off] : 0;
        __syncthreads();
        s[tid] += t;
        __syncthreads();
    }
    if (tid == 255) base_s = atomicAdd(gbase, s[255]);
    int excl = s[tid] - p3;
    __syncthreads();
    int e0 = base_s + excl;
    int e1 = e0 + tot.x, e2 = e1 + tot.y, e3 = e2 + tot.z;
    *(int4*)&deg[i] = tot;
    int4 st; st.x = e0; st.y = e1; st.z = e2; st.w = e3;
    *(int4*)&start[i] = st;
    int cx = e0, cy = e1, cz = e2, cw = e3;
    #pragma unroll
    for (int bk = 0; bk < 8; ++bk) {
        int4 c; c.x = cx; c.y = cy; c.z = cz; c.w = cw;
        *(int4*)&cursor8[bk * N_PAD + i] = c;
        cx += d8[bk].x; cy += d8[bk].y; cz += d8[bk].z; cw += d8[bk].w;
    }
}

// ---------------------------------------------------------------------------
// build_csr: XCD-local cursor atomics (same bank mapping as hist)
// ---------------------------------------------------------------------------
__global__ __launch_bounds__(256) void build_csr(const int* __restrict__ ei,
                                                 int* __restrict__ cursor8,
                                                 int* __restrict__ csr_src)
{
    const int blk = blockIdx.x;
    int e = blk * 256 + threadIdx.x;
    if (e >= N_EDGES) return;
    int d = ei[N_EDGES + e];
    int pos = atomicAdd(&cursor8[(blk & 7) * N_PAD + d], 1);
    csr_src[pos] = ei[e];
}

// ---------------------------------------------------------------------------
// mid: fused gather1(+bias+right+relu) -> LDS h-tile (32 nodes) -> gemm2 MFMA
// gather loop unrolled x4 for MLP
// ---------------------------------------------------------------------------
__global__ __launch_bounds__(256) void mid(
    const unsigned short* __restrict__ xl,
    const unsigned short* __restrict__ xr,
    const int* __restrict__ start,
    const int* __restrict__ deg,
    const int* __restrict__ csr_src,
    const float* __restrict__ b1l,
    const unsigned short* __restrict__ wbf2,   // [64][64] bf16
    unsigned short* __restrict__ hl,
    unsigned short* __restrict__ hr)
{
    __shared__ unsigned short hs[32 * 64];     // 4KB, swizzled rows of 128B

    const int tid = threadIdx.x;
    const int nd  = tid >> 3;                  // local node 0..31
    const int q   = tid & 7;                   // feat chunk 0..7
    const int node = blockIdx.x * 32 + nd;

    const int beg = start[node];
    const int dg  = deg[node];

    float acc[8] = {0.f,0.f,0.f,0.f,0.f,0.f,0.f,0.f};
    int i = 0;
    for (; i + 4 <= dg; i += 4) {
        int s0 = csr_src[beg + i];
        int s1 = csr_src[beg + i + 1];
        int s2 = csr_src[beg + i + 2];
        int s3 = csr_src[beg + i + 3];
        u16x8 v0 = *(const u16x8*)&xl[s0 * 64 + 8 * q];
        u16x8 v1 = *(const u16x8*)&xl[s1 * 64 + 8 * q];
        u16x8 v2 = *(const u16x8*)&xl[s2 * 64 + 8 * q];
        u16x8 v3 = *(const u16x8*)&xl[s3 * 64 + 8 * q];
        #pragma unroll
        for (int j = 0; j < 8; ++j)
            acc[j] += (bf2f(v0[j]) + bf2f(v1[j])) + (bf2f(v2[j]) + bf2f(v3[j]));
    }
    for (; i < dg; ++i) {
        int s = csr_src[beg + i];
        u16x8 v = *(const u16x8*)&xl[s * 64 + 8 * q];
        #pragma unroll
        for (int j = 0; j < 8; ++j) acc[j] += bf2f(v[j]);
    }
    const float inv = 1.0f / (float)max(dg, 1);
    u16x8 rv = *(const u16x8*)&xr[node * 64 + 8 * q];
    float4 b0 = *(const float4*)&b1l[8 * q];
    float4 b1 = *(const float4*)&b1l[8 * q + 4];
    float bb[8] = {b0.x,b0.y,b0.z,b0.w,b1.x,b1.y,b1.z,b1.w};
    u16x8 hv;
    #pragma unroll
    for (int j = 0; j < 8; ++j) {
        float o = fmaf(acc[j], inv, bb[j]) + bf2f(rv[j]);
        hv[j] = f2bf(fmaxf(o, 0.f));
    }
    *(u16x8*)((char*)hs + nd * 128 + ((q * 16) ^ ((nd & 7) << 4))) = hv;
    __syncthreads();

    const int wv   = tid >> 6;
    const int l    = tid & 63;
    const int lrow = l & 15;
    const int hi   = l >> 4;

    f32x4 a0 = (f32x4){0.f,0.f,0.f,0.f};
    f32x4 a1 = (f32x4){0.f,0.f,0.f,0.f};
    #pragma unroll
    for (int kt = 0; kt < 2; ++kt) {
        const int kin = kt * 64 + hi * 16;
        bf16x8 bf0 = __builtin_bit_cast(bf16x8, *(const u16x8*)
            ((const char*)hs + lrow * 128 + (kin ^ ((lrow & 7) << 4))));
        bf16x8 bf1 = __builtin_bit_cast(bf16x8, *(const u16x8*)
            ((const char*)hs + (16 + lrow) * 128 + (kin ^ ((lrow & 7) << 4))));
        bf16x8 a = ldfrag_bf16(wbf2 + (wv * 16 + lrow) * 64 + kt * 32 + hi * 8);
        a0 = __builtin_amdgcn_mfma_f32_16x16x32_bf16(a, bf0, a0, 0, 0, 0);
        a1 = __builtin_amdgcn_mfma_f32_16x16x32_bf16(a, bf1, a1, 0, 0, 0);
    }

    const int n0 = blockIdx.x * 32 + lrow;
    const int n1 = n0 + 16;
    const int feat = wv * 16 + hi * 4;
    u16x4 p0, p1;
    p0[0]=f2bf(a0[0]); p0[1]=f2bf(a0[1]); p0[2]=f2bf(a0[2]); p0[3]=f2bf(a0[3]);
    p1[0]=f2bf(a1[0]); p1[1]=f2bf(a1[1]); p1[2]=f2bf(a1[2]); p1[3]=f2bf(a1[3]);
    if (wv < 2) {
        *(u16x4*)&hl[n0 * 32 + feat] = p0;
        *(u16x4*)&hl[n1 * 32 + feat] = p1;
    } else {
        *(u16x4*)&hr[n0 * 32 + (feat - 32)] = p0;
        *(u16x4*)&hr[n1 * 32 + (feat - 32)] = p1;
    }
}

// ---------------------------------------------------------------------------
// gather2: out[n] = (sum hl[s]) / max(deg,1) + b2 + hr[n]  (f32 out), unroll x4
// ---------------------------------------------------------------------------
__global__ __launch_bounds__(256) void gather2(
    const unsigned short* __restrict__ hl,
    const int* __restrict__ start,
    const int* __restrict__ deg,
    const int* __restrict__ csr_src,
    const float* __restrict__ b2l,
    const unsigned short* __restrict__ hr,
    float* __restrict__ out)
{
    int t = blockIdx.x * 256 + threadIdx.x;
    int n = t >> 2;
    int q = t & 3;
    if (n >= N_NODES) return;
    int beg = start[n], dg = deg[n];

    float acc[8] = {0.f,0.f,0.f,0.f,0.f,0.f,0.f,0.f};
    int i = 0;
    for (; i + 4 <= dg; i += 4) {
        int s0 = csr_src[beg + i];
        int s1 = csr_src[beg + i + 1];
        int s2 = csr_src[beg + i + 2];
        int s3 = csr_src[beg + i + 3];
        u16x8 v0 = *(const u16x8*)&hl[s0 * 32 + 8 * q];
        u16x8 v1 = *(const u16x8*)&hl[s1 * 32 + 8 * q];
        u16x8 v2 = *(const u16x8*)&hl[s2 * 32 + 8 * q];
        u16x8 v3 = *(const u16x8*)&hl[s3 * 32 + 8 * q];
        #pragma unroll
        for (int j = 0; j < 8; ++j)
            acc[j] += (bf2f(v0[j]) + bf2f(v1[j])) + (bf2f(v2[j]) + bf2f(v3[j]));
    }
    for (; i < dg; ++i) {
        int s = csr_src[beg + i];
        u16x8 v = *(const u16x8*)&hl[s * 32 + 8 * q];
        #pragma unroll
        for (int j = 0; j < 8; ++j) acc[j] += bf2f(v[j]);
    }
    float inv = 1.0f / (float)max(dg, 1);
    u16x8 rv = *(const u16x8*)&hr[n * 32 + 8 * q];
    float4 b0 = *(const float4*)&b2l[8 * q];
    float4 b1 = *(const float4*)&b2l[8 * q + 4];
    float bb[8] = {b0.x,b0.y,b0.z,b0.w,b1.x,b1.y,b1.z,b1.w};
    float o[8];
    #pragma unroll
    for (int j = 0; j < 8; ++j)
        o[j] = fmaf(acc[j], inv, bb[j]) + bf2f(rv[j]);
    float* op = out + n * 32 + 8 * q;
    *(float4*)op       = make_float4(o[0], o[1], o[2], o[3]);
    *(float4*)(op + 4) = make_float4(o[4], o[5], o[6], o[7]);
}

extern "C" void kernel_launch(void* const* d_in, const int* in_sizes, int n_in,
                              void* d_out, int out_size, void* d_ws, size_t ws_size,
                              hipStream_t stream)
{
    const float* x   = (const float*)d_in[0];
    const int*   ei  = (const int*)d_in[1];   // int32 (JAX x64 disabled)
    const float* w1l = (const float*)d_in[2];
    const float* b1l = (const float*)d_in[3];
    const float* w1r = (const float*)d_in[4];
    const float* w2l = (const float*)d_in[5];
    const float* b2l = (const float*)d_in[6];
    const float* w2r = (const float*)d_in[7];
    float* out = (float*)d_out;

    char* ws = (char*)d_ws;
    unsigned short* xl      = (unsigned short*)(ws + 0);          // 100000x64 bf16
    unsigned short* xr      = (unsigned short*)(ws + 12800000);
    unsigned short* hl      = (unsigned short*)(ws + 25600000);   // 100000x32 bf16
    unsigned short* hr      = (unsigned short*)(ws + 32000000);
    int*   csr_src = (int*)(ws + 38400000);                       // 2.4MB
    int*   deg8    = (int*)(ws + 40800000);                       // 8 x N_PAD
    int*   cursor8 = (int*)(ws + 44011264);                       // 8 x N_PAD
    int*   deg     = (int*)(ws + 47222528);                       // N_PAD
    int*   start   = (int*)(ws + 47623936);                       // N_PAD
    unsigned short* wbf1 = (unsigned short*)(ws + 48025344);      // [128][128]
    unsigned short* wbf2 = (unsigned short*)(ws + 48058112);      // [64][64]
    int*   gbase   = (int*)(ws + 48066304);

    // 1. prep
    prep<<<392, 256, 0, stream>>>(w1l, w1r, w2l, w2r, wbf1, wbf2, deg8, gbase);
    // 2. layer-1 GEMM + histogram (merged)
    front<<<G1_BLOCKS + HIST_BLOCKS, 256, 0, stream>>>(x, wbf1, ei, xl, xr, deg8);
    // 3. scan
    scan_atomic<<<NB1, 256, 0, stream>>>(deg8, gbase, deg, start, cursor8);
    // 4. bucket edges
    build_csr<<<HIST_BLOCKS, 256, 0, stream>>>(ei, cursor8, csr_src);
    // 5. fused gather1 + epilogue + gemm2
    mid<<<MID_BLOCKS, 256, 0, stream>>>(xl, xr, start, deg, csr_src, b1l, wbf2, hl, hr);
    // 6. gather2 + epilogue -> out
    gather2<<<(N_NODES * 4 + 255) / 256, 256, 0, stream>>>(hl, start, deg, csr_src, b2l, hr, out);
}

// Round 12
// 110.364 us; speedup vs baseline: 1.1869x; 1.0618x over previous
//
#include <hip/hip_runtime.h>

#define N_NODES 100000
#define N_EDGES 600000
#define N_PAD   100352      // N_NODES rounded to 1024 (scan tiles)
#define NB1     98          // N_PAD / 1024
#define G1_TILES 3125       // N_NODES / 32 exactly
#define G1_TPB   4          // tiles per gemm block
#define G1_BLOCKS 782       // ceil(3125/4)
#define HIST_EPB 2048       // edges per hist block (8/thread)
#define HIST_BLOCKS 293     // ceil(600000/2048)
#define MID_BLOCKS 3125     // N_NODES / 32 exactly

typedef __bf16 bf16x8 __attribute__((ext_vector_type(8)));
typedef float  f32x4  __attribute__((ext_vector_type(4)));
typedef unsigned short u16x8 __attribute__((ext_vector_type(8)));
typedef unsigned short u16x4 __attribute__((ext_vector_type(4)));

__device__ inline unsigned short f2bf(float f) {
    __bf16 h = (__bf16)f;
    return __builtin_bit_cast(unsigned short, h);
}
__device__ inline float bf2f(unsigned short u) {
    return __builtin_bit_cast(float, ((unsigned)u) << 16);
}
__device__ inline bf16x8 ldfrag_bf16(const unsigned short* p) {
    u16x8 v = *(const u16x8*)p;
    return __builtin_bit_cast(bf16x8, v);
}

// ---------------------------------------------------------------------------
// prep: zero deg8 (8 banks) + gbase, convert W1/W2 to bf16
// ---------------------------------------------------------------------------
__global__ __launch_bounds__(256) void prep(
    const float* __restrict__ w1l, const float* __restrict__ w1r,
    const float* __restrict__ w2l, const float* __restrict__ w2r,
    unsigned short* __restrict__ wbf1, unsigned short* __restrict__ wbf2,
    int* __restrict__ deg8, int* __restrict__ gbase)
{
    int i = blockIdx.x * 256 + threadIdx.x;
    #pragma unroll
    for (int bk = 0; bk < 8; ++bk) deg8[bk * N_PAD + i] = 0;
    if (i == 0) gbase[0] = 0;
    if (i < 16384) {
        int row = i >> 7, k = i & 127;
        float v = (row < 64) ? w1l[(row << 7) + k] : w1r[((row - 64) << 7) + k];
        wbf1[i] = f2bf(v);
    } else if (i < 20480) {
        int j = i - 16384;
        int row = j >> 6, k = j & 63;
        float v = (row < 32) ? w2l[(row << 6) + k] : w2r[((row - 32) << 6) + k];
        wbf2[j] = f2bf(v);
    }
}

// ---------------------------------------------------------------------------
// front: blocks [0,G1_BLOCKS): layer-1 GEMM — W1 staged to LDS once,
//        4 node-tiles/block with double-buffered x staging (1 barrier/tile);
//        blocks [G1_BLOCKS,+HIST_BLOCKS): histogram, 8 edges/thread.
// ---------------------------------------------------------------------------
__global__ __launch_bounds__(256) void front(
    const float* __restrict__ x,
    const unsigned short* __restrict__ wbf1,   // [128][128] bf16
    const int* __restrict__ ei,
    unsigned short* __restrict__ xl,
    unsigned short* __restrict__ xr,
    int* __restrict__ deg8)
{
    const int b   = blockIdx.x;
    const int tid = threadIdx.x;

    if (b >= G1_BLOCKS) {
        const int hb = b - G1_BLOCKS;
        const int e0 = hb * HIST_EPB + tid;
        int dst[8];
        #pragma unroll
        for (int r = 0; r < 8; ++r) {
            int e = e0 + r * 256;
            dst[r] = (e < N_EDGES) ? ei[N_EDGES + e] : -1;
        }
        const int bank = (hb & 7) * N_PAD;
        #pragma unroll
        for (int r = 0; r < 8; ++r)
            if (dst[r] >= 0) atomicAdd(&deg8[bank + dst[r]], 1);
        return;
    }

    __shared__ unsigned short wlds[128 * 128];   // 32KB, swizzled 256B rows
    __shared__ unsigned short xs[2][32 * 128];   // 2 x 8KB double buffer

    // ---- stage W1 to LDS once: 2048 chunks of 16B, 16 chunks per 256B row ----
    #pragma unroll
    for (int i = 0; i < 8; ++i) {
        int idx = i * 256 + tid;            // 16B chunk id (2048 total)
        int row = idx >> 4;                 // 0..127
        int off = (idx & 15) << 4;          // byte offset in 256B row
        u16x8 v = *(const u16x8*)(wbf1 + row * 128 + (off >> 1));
        *(u16x8*)((char*)wlds + row * 256 + (off ^ ((row & 7) << 4))) = v;
    }

    const int t0     = b * G1_TPB;
    const int ntiles = (G1_TILES - t0 < G1_TPB) ? (G1_TILES - t0) : G1_TPB;

    const int wv   = tid >> 6;
    const int l    = tid & 63;
    const int lrow = l & 15;
    const int hi   = l >> 4;

    const int sr0  = tid >> 4;              // staging row (round 0), 0..15
    const int soff = (tid & 15) << 4;       // byte offset within 256B bf16 row

    float4 pf[4];                           // prefetch regs (2 rounds x 32B)

    // SLOAD: issue global loads for tile t into pf
    #define SLOAD(t) do {                                                      \
        _Pragma("unroll")                                                      \
        for (int r = 0; r < 2; ++r) {                                          \
            const float* src = x + (size_t)((t) * 32 + sr0 + r * 16) * 128     \
                                 + (soff >> 1);                                \
            pf[2*r]   = *(const float4*)src;                                   \
            pf[2*r+1] = *(const float4*)(src + 4);                             \
        }                                                                      \
    } while (0)

    // SWRITE: convert + write pf into xs[bf]
    #define SWRITE(bf) do {                                                    \
        _Pragma("unroll")                                                      \
        for (int r = 0; r < 2; ++r) {                                          \
            int row = sr0 + r * 16;                                            \
            u16x8 o;                                                           \
            o[0]=f2bf(pf[2*r].x);   o[1]=f2bf(pf[2*r].y);                      \
            o[2]=f2bf(pf[2*r].z);   o[3]=f2bf(pf[2*r].w);                      \
            o[4]=f2bf(pf[2*r+1].x); o[5]=f2bf(pf[2*r+1].y);                    \
            o[6]=f2bf(pf[2*r+1].z); o[7]=f2bf(pf[2*r+1].w);                    \
            *(u16x8*)((char*)&xs[bf][0] + row * 256                            \
                      + (soff ^ ((row & 7) << 4))) = o;                        \
        }                                                                      \
    } while (0)

    SLOAD(t0);
    SWRITE(0);
    __syncthreads();

    for (int tt = 0; tt < ntiles; ++tt) {
        if (tt + 1 < ntiles) SLOAD(t0 + tt + 1);

        const char* xb = (const char*)&xs[tt & 1][0];
        f32x4 acc[2][2];
        #pragma unroll
        for (int nt = 0; nt < 2; ++nt)
            #pragma unroll
            for (int ft = 0; ft < 2; ++ft) acc[nt][ft] = (f32x4){0.f,0.f,0.f,0.f};

        #pragma unroll
        for (int kt = 0; kt < 4; ++kt) {
            const int koff = kt * 64 + hi * 16;
            const int r0 = lrow, r1 = 16 + lrow;
            bf16x8 b0 = __builtin_bit_cast(bf16x8, *(const u16x8*)
                (xb + r0 * 256 + (koff ^ ((r0 & 7) << 4))));
            bf16x8 b1 = __builtin_bit_cast(bf16x8, *(const u16x8*)
                (xb + r1 * 256 + (koff ^ ((r1 & 7) << 4))));
            #pragma unroll
            for (int ft = 0; ft < 2; ++ft) {
                const int fr = wv * 32 + ft * 16 + lrow;
                bf16x8 a = __builtin_bit_cast(bf16x8, *(const u16x8*)
                    ((char*)wlds + fr * 256 + (koff ^ ((fr & 7) << 4))));
                acc[0][ft] = __builtin_amdgcn_mfma_f32_16x16x32_bf16(a, b0, acc[0][ft], 0, 0, 0);
                acc[1][ft] = __builtin_amdgcn_mfma_f32_16x16x32_bf16(a, b1, acc[1][ft], 0, 0, 0);
            }
        }

        if (tt + 1 < ntiles) SWRITE((tt + 1) & 1);

        const int nbase = (t0 + tt) * 32;   // all tiles full: no guards
        #pragma unroll
        for (int nt = 0; nt < 2; ++nt) {
            const int node = nbase + nt * 16 + lrow;
            #pragma unroll
            for (int ft = 0; ft < 2; ++ft) {
                const int feat = wv * 32 + ft * 16 + hi * 4;
                u16x4 p;
                p[0] = f2bf(acc[nt][ft][0]); p[1] = f2bf(acc[nt][ft][1]);
                p[2] = f2bf(acc[nt][ft][2]); p[3] = f2bf(acc[nt][ft][3]);
                if (wv < 2) *(u16x4*)&xl[node * 64 + feat]        = p;
                else        *(u16x4*)&xr[node * 64 + (feat - 64)] = p;
            }
        }
        __syncthreads();
    }
    #undef SLOAD
    #undef SWRITE
}

// ---------------------------------------------------------------------------
// scan: sum 8 banks -> deg; block scan + atomic global base -> start;
// per-bank exclusive prefix -> cursor8
// ---------------------------------------------------------------------------
__global__ __launch_bounds__(256) void scan_atomic(
    const int* __restrict__ deg8, int* __restrict__ gbase,
    int* __restrict__ deg, int* __restrict__ start, int* __restrict__ cursor8)
{
    __shared__ int s[256];
    __shared__ int base_s;
    int b = blockIdx.x, tid = threadIdx.x;
    int i = b * 1024 + tid * 4;
    int4 d8[8];
    #pragma unroll
    for (int bk = 0; bk < 8; ++bk) d8[bk] = *(const int4*)&deg8[bk * N_PAD + i];
    int4 tot = d8[0];
    #pragma unroll
    for (int bk = 1; bk < 8; ++bk) {
        tot.x += d8[bk].x; tot.y += d8[bk].y; tot.z += d8[bk].z; tot.w += d8[bk].w;
    }
    int p0 = tot.x, p1 = p0 + tot.y, p2 = p1 + tot.z, p3 = p2 + tot.w;
    s[tid] = p3;
    __syncthreads();
    for (int off = 1; off < 256; off <<= 1) {
        int t = (tid >= off) ? s[tid - off] : 0;
        __syncthreads();
        s[tid] += t;
        __syncthreads();
    }
    if (tid == 255) base_s = atomicAdd(gbase, s[255]);
    int excl = s[tid] - p3;
    __syncthreads();
    int e0 = base_s + excl;
    int e1 = e0 + tot.x, e2 = e1 + tot.y, e3 = e2 + tot.z;
    *(int4*)&deg[i] = tot;
    int4 st; st.x = e0; st.y = e1; st.z = e2; st.w = e3;
    *(int4*)&start[i] = st;
    int cx = e0, cy = e1, cz = e2, cw = e3;
    #pragma unroll
    for (int bk = 0; bk < 8; ++bk) {
        int4 c; c.x = cx; c.y = cy; c.z = cz; c.w = cw;
        *(int4*)&cursor8[bk * N_PAD + i] = c;
        cx += d8[bk].x; cy += d8[bk].y; cz += d8[bk].z; cw += d8[bk].w;
    }
}

// ---------------------------------------------------------------------------
// build_csr: XCD-local cursor atomics (same bank mapping as hist: e/HIST_EPB)
// ---------------------------------------------------------------------------
__global__ __launch_bounds__(256) void build_csr(const int* __restrict__ ei,
                                                 int* __restrict__ cursor8,
                                                 int* __restrict__ csr_src)
{
    int e = blockIdx.x * 256 + threadIdx.x;
    if (e >= N_EDGES) return;
    int d = ei[N_EDGES + e];
    int bank = ((e / HIST_EPB) & 7) * N_PAD;
    int pos = atomicAdd(&cursor8[bank + d], 1);
    csr_src[pos] = ei[e];
}

// ---------------------------------------------------------------------------
// mid: fused gather1(+bias+right+relu) -> LDS h-tile (32 nodes) -> gemm2 MFMA
// ---------------------------------------------------------------------------
__global__ __launch_bounds__(256) void mid(
    const unsigned short* __restrict__ xl,
    const unsigned short* __restrict__ xr,
    const int* __restrict__ start,
    const int* __restrict__ deg,
    const int* __restrict__ csr_src,
    const float* __restrict__ b1l,
    const unsigned short* __restrict__ wbf2,   // [64][64] bf16
    unsigned short* __restrict__ hl,
    unsigned short* __restrict__ hr)
{
    __shared__ unsigned short hs[32 * 64];     // 4KB, swizzled rows of 128B

    const int tid = threadIdx.x;
    const int nd  = tid >> 3;                  // local node 0..31
    const int q   = tid & 7;                   // feat chunk 0..7
    const int node = blockIdx.x * 32 + nd;

    const int beg = start[node];
    const int dg  = deg[node];

    float acc[8] = {0.f,0.f,0.f,0.f,0.f,0.f,0.f,0.f};
    int i = 0;
    for (; i + 4 <= dg; i += 4) {
        int s0 = csr_src[beg + i];
        int s1 = csr_src[beg + i + 1];
        int s2 = csr_src[beg + i + 2];
        int s3 = csr_src[beg + i + 3];
        u16x8 v0 = *(const u16x8*)&xl[s0 * 64 + 8 * q];
        u16x8 v1 = *(const u16x8*)&xl[s1 * 64 + 8 * q];
        u16x8 v2 = *(const u16x8*)&xl[s2 * 64 + 8 * q];
        u16x8 v3 = *(const u16x8*)&xl[s3 * 64 + 8 * q];
        #pragma unroll
        for (int j = 0; j < 8; ++j)
            acc[j] += (bf2f(v0[j]) + bf2f(v1[j])) + (bf2f(v2[j]) + bf2f(v3[j]));
    }
    for (; i < dg; ++i) {
        int s = csr_src[beg + i];
        u16x8 v = *(const u16x8*)&xl[s * 64 + 8 * q];
        #pragma unroll
        for (int j = 0; j < 8; ++j) acc[j] += bf2f(v[j]);
    }
    const float inv = 1.0f / (float)max(dg, 1);
    u16x8 rv = *(const u16x8*)&xr[node * 64 + 8 * q];
    float4 b0 = *(const float4*)&b1l[8 * q];
    float4 b1 = *(const float4*)&b1l[8 * q + 4];
    float bb[8] = {b0.x,b0.y,b0.z,b0.w,b1.x,b1.y,b1.z,b1.w};
    u16x8 hv;
    #pragma unroll
    for (int j = 0; j < 8; ++j) {
        float o = fmaf(acc[j], inv, bb[j]) + bf2f(rv[j]);
        hv[j] = f2bf(fmaxf(o, 0.f));
    }
    *(u16x8*)((char*)hs + nd * 128 + ((q * 16) ^ ((nd & 7) << 4))) = hv;
    __syncthreads();

    const int wv   = tid >> 6;
    const int l    = tid & 63;
    const int lrow = l & 15;
    const int hi   = l >> 4;

    f32x4 a0 = (f32x4){0.f,0.f,0.f,0.f};
    f32x4 a1 = (f32x4){0.f,0.f,0.f,0.f};
    #pragma unroll
    for (int kt = 0; kt < 2; ++kt) {
        const int kin = kt * 64 + hi * 16;
        bf16x8 bf0 = __builtin_bit_cast(bf16x8, *(const u16x8*)
            ((const char*)hs + lrow * 128 + (kin ^ ((lrow & 7) << 4))));
        bf16x8 bf1 = __builtin_bit_cast(bf16x8, *(const u16x8*)
            ((const char*)hs + (16 + lrow) * 128 + (kin ^ ((lrow & 7) << 4))));
        bf16x8 a = ldfrag_bf16(wbf2 + (wv * 16 + lrow) * 64 + kt * 32 + hi * 8);
        a0 = __builtin_amdgcn_mfma_f32_16x16x32_bf16(a, bf0, a0, 0, 0, 0);
        a1 = __builtin_amdgcn_mfma_f32_16x16x32_bf16(a, bf1, a1, 0, 0, 0);
    }

    const int n0 = blockIdx.x * 32 + lrow;
    const int n1 = n0 + 16;
    const int feat = wv * 16 + hi * 4;
    u16x4 p0, p1;
    p0[0]=f2bf(a0[0]); p0[1]=f2bf(a0[1]); p0[2]=f2bf(a0[2]); p0[3]=f2bf(a0[3]);
    p1[0]=f2bf(a1[0]); p1[1]=f2bf(a1[1]); p1[2]=f2bf(a1[2]); p1[3]=f2bf(a1[3]);
    if (wv < 2) {
        *(u16x4*)&hl[n0 * 32 + feat] = p0;
        *(u16x4*)&hl[n1 * 32 + feat] = p1;
    } else {
        *(u16x4*)&hr[n0 * 32 + (feat - 32)] = p0;
        *(u16x4*)&hr[n1 * 32 + (feat - 32)] = p1;
    }
}

// ---------------------------------------------------------------------------
// gather2: out[n] = (sum hl[s]) / max(deg,1) + b2 + hr[n]  (f32 out), unroll x4
// ---------------------------------------------------------------------------
__global__ __launch_bounds__(256) void gather2(
    const unsigned short* __restrict__ hl,
    const int* __restrict__ start,
    const int* __restrict__ deg,
    const int* __restrict__ csr_src,
    const float* __restrict__ b2l,
    const unsigned short* __restrict__ hr,
    float* __restrict__ out)
{
    int t = blockIdx.x * 256 + threadIdx.x;
    int n = t >> 2;
    int q = t & 3;
    if (n >= N_NODES) return;
    int beg = start[n], dg = deg[n];

    float acc[8] = {0.f,0.f,0.f,0.f,0.f,0.f,0.f,0.f};
    int i = 0;
    for (; i + 4 <= dg; i += 4) {
        int s0 = csr_src[beg + i];
        int s1 = csr_src[beg + i + 1];
        int s2 = csr_src[beg + i + 2];
        int s3 = csr_src[beg + i + 3];
        u16x8 v0 = *(const u16x8*)&hl[s0 * 32 + 8 * q];
        u16x8 v1 = *(const u16x8*)&hl[s1 * 32 + 8 * q];
        u16x8 v2 = *(const u16x8*)&hl[s2 * 32 + 8 * q];
        u16x8 v3 = *(const u16x8*)&hl[s3 * 32 + 8 * q];
        #pragma unroll
        for (int j = 0; j < 8; ++j)
            acc[j] += (bf2f(v0[j]) + bf2f(v1[j])) + (bf2f(v2[j]) + bf2f(v3[j]));
    }
    for (; i < dg; ++i) {
        int s = csr_src[beg + i];
        u16x8 v = *(const u16x8*)&hl[s * 32 + 8 * q];
        #pragma unroll
        for (int j = 0; j < 8; ++j) acc[j] += bf2f(v[j]);
    }
    float inv = 1.0f / (float)max(dg, 1);
    u16x8 rv = *(const u16x8*)&hr[n * 32 + 8 * q];
    float4 b0 = *(const float4*)&b2l[8 * q];
    float4 b1 = *(const float4*)&b2l[8 * q + 4];
    float bb[8] = {b0.x,b0.y,b0.z,b0.w,b1.x,b1.y,b1.z,b1.w};
    float o[8];
    #pragma unroll
    for (int j = 0; j < 8; ++j)
        o[j] = fmaf(acc[j], inv, bb[j]) + bf2f(rv[j]);
    float* op = out + n * 32 + 8 * q;
    *(float4*)op       = make_float4(o[0], o[1], o[2], o[3]);
    *(float4*)(op + 4) = make_float4(o[4], o[5], o[6], o[7]);
}

extern "C" void kernel_launch(void* const* d_in, const int* in_sizes, int n_in,
                              void* d_out, int out_size, void* d_ws, size_t ws_size,
                              hipStream_t stream)
{
    const float* x   = (const float*)d_in[0];
    const int*   ei  = (const int*)d_in[1];   // int32 (JAX x64 disabled)
    const float* w1l = (const float*)d_in[2];
    const float* b1l = (const float*)d_in[3];
    const float* w1r = (const float*)d_in[4];
    const float* w2l = (const float*)d_in[5];
    const float* b2l = (const float*)d_in[6];
    const float* w2r = (const float*)d_in[7];
    float* out = (float*)d_out;

    char* ws = (char*)d_ws;
    unsigned short* xl      = (unsigned short*)(ws + 0);          // 100000x64 bf16
    unsigned short* xr      = (unsigned short*)(ws + 12800000);
    unsigned short* hl      = (unsigned short*)(ws + 25600000);   // 100000x32 bf16
    unsigned short* hr      = (unsigned short*)(ws + 32000000);
    int*   csr_src = (int*)(ws + 38400000);                       // 2.4MB
    int*   deg8    = (int*)(ws + 40800000);                       // 8 x N_PAD
    int*   cursor8 = (int*)(ws + 44011264);                       // 8 x N_PAD
    int*   deg     = (int*)(ws + 47222528);                       // N_PAD
    int*   start   = (int*)(ws + 47623936);                       // N_PAD
    unsigned short* wbf1 = (unsigned short*)(ws + 48025344);      // [128][128]
    unsigned short* wbf2 = (unsigned short*)(ws + 48058112);      // [64][64]
    int*   gbase   = (int*)(ws + 48066304);

    // 1. prep
    prep<<<392, 256, 0, stream>>>(w1l, w1r, w2l, w2r, wbf1, wbf2, deg8, gbase);
    // 2. layer-1 GEMM (W in LDS, dbuf x-tiles) + histogram (merged)
    front<<<G1_BLOCKS + HIST_BLOCKS, 256, 0, stream>>>(x, wbf1, ei, xl, xr, deg8);
    // 3. scan
    scan_atomic<<<NB1, 256, 0, stream>>>(deg8, gbase, deg, start, cursor8);
    // 4. bucket edges
    build_csr<<<(N_EDGES + 255) / 256, 256, 0, stream>>>(ei, cursor8, csr_src);
    // 5. fused gather1 + epilogue + gemm2
    mid<<<MID_BLOCKS, 256, 0, stream>>>(xl, xr, start, deg, csr_src, b1l, wbf2, hl, hr);
    // 6. gather2 + epilogue -> out
    gather2<<<(N_NODES * 4 + 255) / 256, 256, 0, stream>>>(hl, start, deg, csr_src, b2l, hr, out);
}

// Round 13
// 109.045 us; speedup vs baseline: 1.2013x; 1.0121x over previous
//
#include <hip/hip_runtime.h>

#define N_NODES 100000
#define N_EDGES 600000
#define N_PAD   100352      // N_NODES rounded to 1024 (scan tiles)
#define NB1     98          // N_PAD / 1024
#define G1_TILES 3125       // N_NODES / 32 exactly
#define G1_TPB   4          // tiles per gemm block
#define G1_BLOCKS 782       // ceil(3125/4)
#define HIST_EPB 2048       // edges per hist block (8/thread)
#define HIST_BLOCKS 293     // ceil(600000/2048)
#define MID_BLOCKS 3125     // N_NODES / 32 exactly

typedef __bf16 bf16x8 __attribute__((ext_vector_type(8)));
typedef float  f32x4  __attribute__((ext_vector_type(4)));
typedef unsigned short u16x8 __attribute__((ext_vector_type(8)));
typedef unsigned short u16x4 __attribute__((ext_vector_type(4)));

__device__ inline unsigned short f2bf(float f) {
    __bf16 h = (__bf16)f;
    return __builtin_bit_cast(unsigned short, h);
}
__device__ inline float bf2f(unsigned short u) {
    return __builtin_bit_cast(float, ((unsigned)u) << 16);
}
__device__ inline bf16x8 ldfrag_bf16(const unsigned short* p) {
    u16x8 v = *(const u16x8*)p;
    return __builtin_bit_cast(bf16x8, v);
}

// ---------------------------------------------------------------------------
// prep: zero deg8 (8 banks) + gbase, convert W1/W2 to bf16
// ---------------------------------------------------------------------------
__global__ __launch_bounds__(256) void prep(
    const float* __restrict__ w1l, const float* __restrict__ w1r,
    const float* __restrict__ w2l, const float* __restrict__ w2r,
    unsigned short* __restrict__ wbf1, unsigned short* __restrict__ wbf2,
    int* __restrict__ deg8, int* __restrict__ gbase)
{
    int i = blockIdx.x * 256 + threadIdx.x;
    #pragma unroll
    for (int bk = 0; bk < 8; ++bk) deg8[bk * N_PAD + i] = 0;
    if (i == 0) gbase[0] = 0;
    if (i < 16384) {
        int row = i >> 7, k = i & 127;
        float v = (row < 64) ? w1l[(row << 7) + k] : w1r[((row - 64) << 7) + k];
        wbf1[i] = f2bf(v);
    } else if (i < 20480) {
        int j = i - 16384;
        int row = j >> 6, k = j & 63;
        float v = (row < 32) ? w2l[(row << 6) + k] : w2r[((row - 32) << 6) + k];
        wbf2[j] = f2bf(v);
    }
}

// ---------------------------------------------------------------------------
// front: blocks [0,G1_BLOCKS): layer-1 GEMM — W1 in LDS, 4 node-tiles/block,
//        double-buffered x staging, epilogue via LDS -> dense 16B line stores;
//        blocks [G1_BLOCKS,+HIST_BLOCKS): histogram, 8 edges/thread.
// ---------------------------------------------------------------------------
__global__ __launch_bounds__(256) void front(
    const float* __restrict__ x,
    const unsigned short* __restrict__ wbf1,   // [128][128] bf16
    const int* __restrict__ ei,
    unsigned short* __restrict__ xl,
    unsigned short* __restrict__ xr,
    int* __restrict__ deg8)
{
    const int b   = blockIdx.x;
    const int tid = threadIdx.x;

    if (b >= G1_BLOCKS) {
        const int hb = b - G1_BLOCKS;
        const int e0 = hb * HIST_EPB + tid;
        int dst[8];
        #pragma unroll
        for (int r = 0; r < 8; ++r) {
            int e = e0 + r * 256;
            dst[r] = (e < N_EDGES) ? ei[N_EDGES + e] : -1;
        }
        const int bank = (hb & 7) * N_PAD;
        #pragma unroll
        for (int r = 0; r < 8; ++r)
            if (dst[r] >= 0) atomicAdd(&deg8[bank + dst[r]], 1);
        return;
    }

    __shared__ unsigned short wlds[128 * 128];   // 32KB, swizzled 256B rows
    __shared__ unsigned short xs[2][32 * 128];   // 2 x 8KB double buffer

    // ---- stage W1 to LDS once: 2048 chunks of 16B, 16 chunks per 256B row ----
    #pragma unroll
    for (int i = 0; i < 8; ++i) {
        int idx = i * 256 + tid;
        int row = idx >> 4;                 // 0..127
        int off = (idx & 15) << 4;
        u16x8 v = *(const u16x8*)(wbf1 + row * 128 + (off >> 1));
        *(u16x8*)((char*)wlds + row * 256 + (off ^ ((row & 7) << 4))) = v;
    }

    const int t0     = b * G1_TPB;
    const int ntiles = (G1_TILES - t0 < G1_TPB) ? (G1_TILES - t0) : G1_TPB;

    const int wv   = tid >> 6;
    const int l    = tid & 63;
    const int lrow = l & 15;
    const int hi   = l >> 4;

    const int sr0  = tid >> 4;              // staging row (round 0), 0..15
    const int soff = (tid & 15) << 4;       // byte offset within 256B bf16 row

    float4 pf[4];                           // prefetch regs

    #define SLOAD(t) do {                                                      \
        _Pragma("unroll")                                                      \
        for (int r = 0; r < 2; ++r) {                                          \
            const float* src = x + (size_t)((t) * 32 + sr0 + r * 16) * 128     \
                                 + (soff >> 1);                                \
            pf[2*r]   = *(const float4*)src;                                   \
            pf[2*r+1] = *(const float4*)(src + 4);                             \
        }                                                                      \
    } while (0)

    #define SWRITE(bf) do {                                                    \
        _Pragma("unroll")                                                      \
        for (int r = 0; r < 2; ++r) {                                          \
            int row = sr0 + r * 16;                                            \
            u16x8 o;                                                           \
            o[0]=f2bf(pf[2*r].x);   o[1]=f2bf(pf[2*r].y);                      \
            o[2]=f2bf(pf[2*r].z);   o[3]=f2bf(pf[2*r].w);                      \
            o[4]=f2bf(pf[2*r+1].x); o[5]=f2bf(pf[2*r+1].y);                    \
            o[6]=f2bf(pf[2*r+1].z); o[7]=f2bf(pf[2*r+1].w);                    \
            *(u16x8*)((char*)&xs[bf][0] + row * 256                            \
                      + (soff ^ ((row & 7) << 4))) = o;                        \
        }                                                                      \
    } while (0)

    SLOAD(t0);
    SWRITE(0);
    __syncthreads();

    for (int tt = 0; tt < ntiles; ++tt) {
        if (tt + 1 < ntiles) SLOAD(t0 + tt + 1);

        char* xb = (char*)&xs[tt & 1][0];
        f32x4 acc[2][2];
        #pragma unroll
        for (int nt = 0; nt < 2; ++nt)
            #pragma unroll
            for (int ft = 0; ft < 2; ++ft) acc[nt][ft] = (f32x4){0.f,0.f,0.f,0.f};

        #pragma unroll
        for (int kt = 0; kt < 4; ++kt) {
            const int koff = kt * 64 + hi * 16;
            const int r0 = lrow, r1 = 16 + lrow;
            bf16x8 b0 = __builtin_bit_cast(bf16x8, *(const u16x8*)
                (xb + r0 * 256 + (koff ^ ((r0 & 7) << 4))));
            bf16x8 b1 = __builtin_bit_cast(bf16x8, *(const u16x8*)
                (xb + r1 * 256 + (koff ^ ((r1 & 7) << 4))));
            #pragma unroll
            for (int ft = 0; ft < 2; ++ft) {
                const int fr = wv * 32 + ft * 16 + lrow;
                bf16x8 a = __builtin_bit_cast(bf16x8, *(const u16x8*)
                    ((char*)wlds + fr * 256 + (koff ^ ((fr & 7) << 4))));
                acc[0][ft] = __builtin_amdgcn_mfma_f32_16x16x32_bf16(a, b0, acc[0][ft], 0, 0, 0);
                acc[1][ft] = __builtin_amdgcn_mfma_f32_16x16x32_bf16(a, b1, acc[1][ft], 0, 0, 0);
            }
        }

        if (tt + 1 < ntiles) SWRITE((tt + 1) & 1);
        __syncthreads();                 // all reads of xs[tt&1] complete

        // ---- stage acc into xs[tt&1] as [32 nodes][xl 128B | xr 128B] ----
        #pragma unroll
        for (int nt = 0; nt < 2; ++nt) {
            const int node = nt * 16 + lrow;
            #pragma unroll
            for (int ft = 0; ft < 2; ++ft) {
                const int fb = (wv * 32 + ft * 16 + hi * 4) * 2;  // byte col [0,256)
                u16x4 p;
                p[0] = f2bf(acc[nt][ft][0]); p[1] = f2bf(acc[nt][ft][1]);
                p[2] = f2bf(acc[nt][ft][2]); p[3] = f2bf(acc[nt][ft][3]);
                *(u16x4*)(xb + node * 256 + (fb ^ ((node & 7) << 4))) = p;
            }
        }
        __syncthreads();

        // ---- dense readout: full 128B lines of xl/xr ----
        const int nbase = (t0 + tt) * 32;
        #pragma unroll
        for (int rr = 0; rr < 2; ++rr) {
            int idx = rr * 256 + tid;
            int row = idx >> 4;
            int off = (idx & 15) << 4;
            u16x8 v = *(const u16x8*)(xb + row * 256 + (off ^ ((row & 7) << 4)));
            if (off < 128) *(u16x8*)&xl[(nbase + row) * 64 + (off >> 1)] = v;
            else           *(u16x8*)&xr[(nbase + row) * 64 + ((off - 128) >> 1)] = v;
        }
        __syncthreads();
    }
    #undef SLOAD
    #undef SWRITE
}

// ---------------------------------------------------------------------------
// scan: sum 8 banks -> deg; block scan + atomic global base -> start;
// per-bank exclusive prefix -> cursor8
// ---------------------------------------------------------------------------
__global__ __launch_bounds__(256) void scan_atomic(
    const int* __restrict__ deg8, int* __restrict__ gbase,
    int* __restrict__ deg, int* __restrict__ start, int* __restrict__ cursor8)
{
    __shared__ int s[256];
    __shared__ int base_s;
    int b = blockIdx.x, tid = threadIdx.x;
    int i = b * 1024 + tid * 4;
    int4 d8[8];
    #pragma unroll
    for (int bk = 0; bk < 8; ++bk) d8[bk] = *(const int4*)&deg8[bk * N_PAD + i];
    int4 tot = d8[0];
    #pragma unroll
    for (int bk = 1; bk < 8; ++bk) {
        tot.x += d8[bk].x; tot.y += d8[bk].y; tot.z += d8[bk].z; tot.w += d8[bk].w;
    }
    int p0 = tot.x, p1 = p0 + tot.y, p2 = p1 + tot.z, p3 = p2 + tot.w;
    s[tid] = p3;
    __syncthreads();
    for (int off = 1; off < 256; off <<= 1) {
        int t = (tid >= off) ? s[tid - off] : 0;
        __syncthreads();
        s[tid] += t;
        __syncthreads();
    }
    if (tid == 255) base_s = atomicAdd(gbase, s[255]);
    int excl = s[tid] - p3;
    __syncthreads();
    int e0 = base_s + excl;
    int e1 = e0 + tot.x, e2 = e1 + tot.y, e3 = e2 + tot.z;
    *(int4*)&deg[i] = tot;
    int4 st; st.x = e0; st.y = e1; st.z = e2; st.w = e3;
    *(int4*)&start[i] = st;
    int cx = e0, cy = e1, cz = e2, cw = e3;
    #pragma unroll
    for (int bk = 0; bk < 8; ++bk) {
        int4 c; c.x = cx; c.y = cy; c.z = cz; c.w = cw;
        *(int4*)&cursor8[bk * N_PAD + i] = c;
        cx += d8[bk].x; cy += d8[bk].y; cz += d8[bk].z; cw += d8[bk].w;
    }
}

// ---------------------------------------------------------------------------
// build_csr: XCD-local cursor atomics (same bank mapping as hist: e/HIST_EPB)
// ---------------------------------------------------------------------------
__global__ __launch_bounds__(256) void build_csr(const int* __restrict__ ei,
                                                 int* __restrict__ cursor8,
                                                 int* __restrict__ csr_src)
{
    int e = blockIdx.x * 256 + threadIdx.x;
    if (e >= N_EDGES) return;
    int d = ei[N_EDGES + e];
    int bank = ((e / HIST_EPB) & 7) * N_PAD;
    int pos = atomicAdd(&cursor8[bank + d], 1);
    csr_src[pos] = ei[e];
}

// ---------------------------------------------------------------------------
// mid: fused gather1(+bias+right+relu) -> LDS h-tile -> gemm2 MFMA,
//      epilogue via LDS -> dense 16B line stores of hl/hr
// ---------------------------------------------------------------------------
__global__ __launch_bounds__(256) void mid(
    const unsigned short* __restrict__ xl,
    const unsigned short* __restrict__ xr,
    const int* __restrict__ start,
    const int* __restrict__ deg,
    const int* __restrict__ csr_src,
    const float* __restrict__ b1l,
    const unsigned short* __restrict__ wbf2,   // [64][64] bf16
    unsigned short* __restrict__ hl,
    unsigned short* __restrict__ hr)
{
    __shared__ unsigned short hs[32 * 64];     // 4KB, swizzled rows of 128B

    const int tid = threadIdx.x;
    const int nd  = tid >> 3;                  // local node 0..31
    const int q   = tid & 7;                   // feat chunk 0..7
    const int node = blockIdx.x * 32 + nd;

    const int beg = start[node];
    const int dg  = deg[node];

    float acc[8] = {0.f,0.f,0.f,0.f,0.f,0.f,0.f,0.f};
    int i = 0;
    for (; i + 4 <= dg; i += 4) {
        int s0 = csr_src[beg + i];
        int s1 = csr_src[beg + i + 1];
        int s2 = csr_src[beg + i + 2];
        int s3 = csr_src[beg + i + 3];
        u16x8 v0 = *(const u16x8*)&xl[s0 * 64 + 8 * q];
        u16x8 v1 = *(const u16x8*)&xl[s1 * 64 + 8 * q];
        u16x8 v2 = *(const u16x8*)&xl[s2 * 64 + 8 * q];
        u16x8 v3 = *(const u16x8*)&xl[s3 * 64 + 8 * q];
        #pragma unroll
        for (int j = 0; j < 8; ++j)
            acc[j] += (bf2f(v0[j]) + bf2f(v1[j])) + (bf2f(v2[j]) + bf2f(v3[j]));
    }
    for (; i < dg; ++i) {
        int s = csr_src[beg + i];
        u16x8 v = *(const u16x8*)&xl[s * 64 + 8 * q];
        #pragma unroll
        for (int j = 0; j < 8; ++j) acc[j] += bf2f(v[j]);
    }
    const float inv = 1.0f / (float)max(dg, 1);
    u16x8 rv = *(const u16x8*)&xr[node * 64 + 8 * q];
    float4 b0 = *(const float4*)&b1l[8 * q];
    float4 b1 = *(const float4*)&b1l[8 * q + 4];
    float bb[8] = {b0.x,b0.y,b0.z,b0.w,b1.x,b1.y,b1.z,b1.w};
    u16x8 hv;
    #pragma unroll
    for (int j = 0; j < 8; ++j) {
        float o = fmaf(acc[j], inv, bb[j]) + bf2f(rv[j]);
        hv[j] = f2bf(fmaxf(o, 0.f));
    }
    *(u16x8*)((char*)hs + nd * 128 + ((q * 16) ^ ((nd & 7) << 4))) = hv;
    __syncthreads();

    const int wv   = tid >> 6;
    const int l    = tid & 63;
    const int lrow = l & 15;
    const int hi   = l >> 4;

    f32x4 a0 = (f32x4){0.f,0.f,0.f,0.f};
    f32x4 a1 = (f32x4){0.f,0.f,0.f,0.f};
    #pragma unroll
    for (int kt = 0; kt < 2; ++kt) {
        const int kin = kt * 64 + hi * 16;
        bf16x8 bf0 = __builtin_bit_cast(bf16x8, *(const u16x8*)
            ((const char*)hs + lrow * 128 + (kin ^ ((lrow & 7) << 4))));
        bf16x8 bf1 = __builtin_bit_cast(bf16x8, *(const u16x8*)
            ((const char*)hs + (16 + lrow) * 128 + (kin ^ ((lrow & 7) << 4))));
        bf16x8 a = ldfrag_bf16(wbf2 + (wv * 16 + lrow) * 64 + kt * 32 + hi * 8);
        a0 = __builtin_amdgcn_mfma_f32_16x16x32_bf16(a, bf0, a0, 0, 0, 0);
        a1 = __builtin_amdgcn_mfma_f32_16x16x32_bf16(a, bf1, a1, 0, 0, 0);
    }
    __syncthreads();                           // hs reads complete

    // ---- stage D into hs as [32 nodes][hl 64B | hr 64B] ----
    {
        const int c2 = (wv * 16 + hi * 4) * 2;     // byte col [0,128)
        u16x4 p0, p1;
        p0[0]=f2bf(a0[0]); p0[1]=f2bf(a0[1]); p0[2]=f2bf(a0[2]); p0[3]=f2bf(a0[3]);
        p1[0]=f2bf(a1[0]); p1[1]=f2bf(a1[1]); p1[2]=f2bf(a1[2]); p1[3]=f2bf(a1[3]);
        const int n0l = lrow, n1l = 16 + lrow;
        *(u16x4*)((char*)hs + n0l * 128 + (c2 ^ ((n0l & 7) << 4))) = p0;
        *(u16x4*)((char*)hs + n1l * 128 + (c2 ^ ((n1l & 7) << 4))) = p1;
    }
    __syncthreads();

    // ---- dense readout: full 64B halves of hl/hr lines ----
    {
        const int row = tid >> 3;
        const int off = (tid & 7) << 4;
        u16x8 v = *(const u16x8*)((char*)hs + row * 128 + (off ^ ((row & 7) << 4)));
        const int gn = blockIdx.x * 32 + row;
        if (off < 64) *(u16x8*)&hl[gn * 32 + (off >> 1)] = v;
        else          *(u16x8*)&hr[gn * 32 + ((off - 64) >> 1)] = v;
    }
}

// ---------------------------------------------------------------------------
// gather2: out[n] = (sum hl[s]) / max(deg,1) + b2 + hr[n]  (f32 out), unroll x4
// ---------------------------------------------------------------------------
__global__ __launch_bounds__(256) void gather2(
    const unsigned short* __restrict__ hl,
    const int* __restrict__ start,
    const int* __restrict__ deg,
    const int* __restrict__ csr_src,
    const float* __restrict__ b2l,
    const unsigned short* __restrict__ hr,
    float* __restrict__ out)
{
    int t = blockIdx.x * 256 + threadIdx.x;
    int n = t >> 2;
    int q = t & 3;
    if (n >= N_NODES) return;
    int beg = start[n], dg = deg[n];

    float acc[8] = {0.f,0.f,0.f,0.f,0.f,0.f,0.f,0.f};
    int i = 0;
    for (; i + 4 <= dg; i += 4) {
        int s0 = csr_src[beg + i];
        int s1 = csr_src[beg + i + 1];
        int s2 = csr_src[beg + i + 2];
        int s3 = csr_src[beg + i + 3];
        u16x8 v0 = *(const u16x8*)&hl[s0 * 32 + 8 * q];
        u16x8 v1 = *(const u16x8*)&hl[s1 * 32 + 8 * q];
        u16x8 v2 = *(const u16x8*)&hl[s2 * 32 + 8 * q];
        u16x8 v3 = *(const u16x8*)&hl[s3 * 32 + 8 * q];
        #pragma unroll
        for (int j = 0; j < 8; ++j)
            acc[j] += (bf2f(v0[j]) + bf2f(v1[j])) + (bf2f(v2[j]) + bf2f(v3[j]));
    }
    for (; i < dg; ++i) {
        int s = csr_src[beg + i];
        u16x8 v = *(const u16x8*)&hl[s * 32 + 8 * q];
        #pragma unroll
        for (int j = 0; j < 8; ++j) acc[j] += bf2f(v[j]);
    }
    float inv = 1.0f / (float)max(dg, 1);
    u16x8 rv = *(const u16x8*)&hr[n * 32 + 8 * q];
    float4 b0 = *(const float4*)&b2l[8 * q];
    float4 b1 = *(const float4*)&b2l[8 * q + 4];
    float bb[8] = {b0.x,b0.y,b0.z,b0.w,b1.x,b1.y,b1.z,b1.w};
    float o[8];
    #pragma unroll
    for (int j = 0; j < 8; ++j)
        o[j] = fmaf(acc[j], inv, bb[j]) + bf2f(rv[j]);
    float* op = out + n * 32 + 8 * q;
    *(float4*)op       = make_float4(o[0], o[1], o[2], o[3]);
    *(float4*)(op + 4) = make_float4(o[4], o[5], o[6], o[7]);
}

extern "C" void kernel_launch(void* const* d_in, const int* in_sizes, int n_in,
                              void* d_out, int out_size, void* d_ws, size_t ws_size,
                              hipStream_t stream)
{
    const float* x   = (const float*)d_in[0];
    const int*   ei  = (const int*)d_in[1];   // int32 (JAX x64 disabled)
    const float* w1l = (const float*)d_in[2];
    const float* b1l = (const float*)d_in[3];
    const float* w1r = (const float*)d_in[4];
    const float* w2l = (const float*)d_in[5];
    const float* b2l = (const float*)d_in[6];
    const float* w2r = (const float*)d_in[7];
    float* out = (float*)d_out;

    char* ws = (char*)d_ws;
    unsigned short* xl      = (unsigned short*)(ws + 0);          // 100000x64 bf16
    unsigned short* xr      = (unsigned short*)(ws + 12800000);
    unsigned short* hl      = (unsigned short*)(ws + 25600000);   // 100000x32 bf16
    unsigned short* hr      = (unsigned short*)(ws + 32000000);
    int*   csr_src = (int*)(ws + 38400000);                       // 2.4MB
    int*   deg8    = (int*)(ws + 40800000);                       // 8 x N_PAD
    int*   cursor8 = (int*)(ws + 44011264);                       // 8 x N_PAD
    int*   deg     = (int*)(ws + 47222528);                       // N_PAD
    int*   start   = (int*)(ws + 47623936);                       // N_PAD
    unsigned short* wbf1 = (unsigned short*)(ws + 48025344);      // [128][128]
    unsigned short* wbf2 = (unsigned short*)(ws + 48058112);      // [64][64]
    int*   gbase   = (int*)(ws + 48066304);

    // 1. prep
    prep<<<392, 256, 0, stream>>>(w1l, w1r, w2l, w2r, wbf1, wbf2, deg8, gbase);
    // 2. layer-1 GEMM + histogram (merged), dense epilogue stores
    front<<<G1_BLOCKS + HIST_BLOCKS, 256, 0, stream>>>(x, wbf1, ei, xl, xr, deg8);
    // 3. scan
    scan_atomic<<<NB1, 256, 0, stream>>>(deg8, gbase, deg, start, cursor8);
    // 4. bucket edges
    build_csr<<<(N_EDGES + 255) / 256, 256, 0, stream>>>(ei, cursor8, csr_src);
    // 5. fused gather1 + epilogue + gemm2, dense epilogue stores
    mid<<<MID_BLOCKS, 256, 0, stream>>>(xl, xr, start, deg, csr_src, b1l, wbf2, hl, hr);
    // 6. gather2 + epilogue -> out
    gather2<<<(N_NODES * 4 + 255) / 256, 256, 0, stream>>>(hl, start, deg, csr_src, b2l, hr, out);
}